// Round 9
// baseline (32.940 us; speedup 1.0000x reference)
//
#include <hip/hip_runtime.h>

// Problem constants
#define B_ 4096
#define S_ 32
#define K_ 1024
#define D_ 128
constexpr float DECAY = 0.99f;
constexpr float OMD   = 0.01f;     // 1 - decay
constexpr float EPS   = 1e-5f;

typedef float          f4  __attribute__((ext_vector_type(4)));
typedef int            i4  __attribute__((ext_vector_type(4)));
typedef unsigned short u16;
typedef u16            us8 __attribute__((ext_vector_type(8)));

// ============ Fast path: 2 kernels, no global atomics, no init ============
// ws layout: [0, B_*S_) u16 idx_T  (256 KB), transposed indices idx_T[s][b].
//
// R9 experiment: ALL PLAIN STORES (no nontemporal). Working set 135 MB fits
// the 256 MB L3; under graph replay the output lines are re-dirtied each
// iteration, so plain stores let L2/L3 absorb the 101 MB of writes at cache
// BW instead of forcing the NT bypass path to HBM (6.9 TB/s).

// Kernel A: z_q gather + idx transpose. 2048 blocks x 256 threads.
// s-major mapping (s = blockIdx&31): all 64 blocks of a given s land on XCD
// s%8 (round-robin dispatch), pinning that s's 512KB emb slice in one L2.
// 64 rows/block; 8 idx loads prefetched -> 8 independent gathers in flight.
__global__ void __launch_bounds__(256)
gather_t_kernel(const int* __restrict__ idx,
                const float* __restrict__ emb,
                float* __restrict__ z_q,
                u16* __restrict__ idx_t) {
    const int s     = blockIdx.x & (S_ - 1);
    const int chunk = blockIdx.x >> 5;          // [0, 64)
    const int g     = threadIdx.x >> 5;         // row group 0..7
    const int lane  = threadIdx.x & 31;

    int kk[8];
#pragma unroll
    for (int it = 0; it < 8; ++it) {
        const int b = chunk * 64 + it * 8 + g;
        kk[it] = idx[b * S_ + s];               // broadcast within 32-lane group
    }
#pragma unroll
    for (int it = 0; it < 8; ++it) {
        const int b = chunk * 64 + it * 8 + g;
        if (lane == 0)                           // direct u16 transpose store
            idx_t[(size_t)s * B_ + b] = (u16)kk[it];
        const f4 val =
            reinterpret_cast<const f4*>(emb)[((size_t)s * K_ + kk[it]) * 32 + lane];
        reinterpret_cast<f4*>(z_q)[((size_t)b * S_ + s) * 32 + lane] = val;
    }
}

// Kernel B: LDS histogram + n[s] + fused EMA/Laplace. 2048 blocks x 256.
// Block i: s = i&31 (XCD-aligned with kernel A's warm emb slice), k-chunk
// c = i>>5 of 16 bins. Scans its s-column of idx_T (8KB, coalesced) into a
// 16-bin LDS histogram; n from closed form n = DECAY*rowsum(ecs[s]) + OMD*B
// (sum_k counts == B exactly). 2 f4/thread EMA tail.
__global__ void __launch_bounds__(256)
ema_hist_kernel(const u16* __restrict__ idx_t,
                const float* __restrict__ emb,
                const float* __restrict__ ecs_in,
                const float* __restrict__ ema_w,
                float* __restrict__ new_ecs_out,
                float* __restrict__ new_ema_w_out,
                float* __restrict__ new_emb_out) {
    const int s     = blockIdx.x & (S_ - 1);
    const int c     = blockIdx.x >> 5;          // k-chunk [0, 64)
    const int t     = threadIdx.x;
    const int kbase = c * 16;

    __shared__ int   hist[16];
    __shared__ float red[4];
    __shared__ float n_sh;
    if (t < 16) hist[t] = 0;
    __syncthreads();

    // Histogram scan: 4096 u16 = 512 ushort8; 2 per thread, coalesced.
    const us8* col = reinterpret_cast<const us8*>(idx_t + (size_t)s * B_);
#pragma unroll
    for (int it = 0; it < 2; ++it) {
        const us8 v = col[it * 256 + t];
#pragma unroll
        for (int j = 0; j < 8; ++j) {
            const unsigned u = (unsigned)v[j] - (unsigned)kbase;
            if (u < 16u) atomicAdd(&hist[u], 1);
        }
    }

    // n[s] via closed form.
    const f4 v = reinterpret_cast<const f4*>(ecs_in + s * K_)[t];
    float local = v.x + v.y + v.z + v.w;
#pragma unroll
    for (int off = 1; off < 64; off <<= 1) local += __shfl_xor(local, off);
    if ((t & 63) == 0) red[t >> 6] = local;
    __syncthreads();                 // also publishes hist atomics
    if (t == 0)
        n_sh = DECAY * (red[0] + red[1] + red[2] + red[3]) + OMD * (float)B_;
    __syncthreads();
    const float n = n_sh;
    const float denom_inv = 1.0f / (n + (float)K_ * EPS);

    // Fused EMA elementwise: 512 f4 per block (16 bins x 32 f4).
    const size_t base = ((size_t)s * K_ + kbase) * 32;   // f4 base
#pragma unroll
    for (int it = 0; it < 2; ++it) {
        const int    off = it * 256 + t;
        const int    ub  = off >> 5;             // local bin [0, 16)
        const size_t e   = base + off;           // global f4 index
        const int    sk  = (int)(e >> 5);
        const float ccount = (float)hist[ub];
        const float ne = DECAY * ecs_in[sk] + OMD * ccount;
        const float cs = (ne + EPS) * denom_inv * n;
        if ((off & 31) == 0) new_ecs_out[sk] = ne;

        const f4 w  = reinterpret_cast<const f4*>(ema_w)[e];
        const f4 em = reinterpret_cast<const f4*>(emb)[e];
        f4 nw;
        nw.x = DECAY * w.x + OMD * ccount * em.x;
        nw.y = DECAY * w.y + OMD * ccount * em.y;
        nw.z = DECAY * w.z + OMD * ccount * em.z;
        nw.w = DECAY * w.w + OMD * ccount * em.w;
        reinterpret_cast<f4*>(new_ema_w_out)[e] = nw;
        const float inv = 1.0f / cs;
        f4 nb;
        nb.x = nw.x * inv;
        nb.y = nw.y * inv;
        nb.z = nw.z * inv;
        nb.w = nw.w * inv;
        reinterpret_cast<f4*>(new_emb_out)[e] = nb;
    }
}

// ============ Fallback path (proven R6 structure), used if ws < 256 KB ============

__global__ void __launch_bounds__(256)
init_kernel(const float* __restrict__ ecs_in,
            int* __restrict__ counts,
            float* __restrict__ n_out) {
    const int s = blockIdx.x;
    const int t = threadIdx.x;
    reinterpret_cast<i4*>(counts + s * K_)[t] = i4{0, 0, 0, 0};
    const f4 v = reinterpret_cast<const f4*>(ecs_in + s * K_)[t];
    float local = v.x + v.y + v.z + v.w;
#pragma unroll
    for (int off = 1; off < 64; off <<= 1) local += __shfl_xor(local, off);
    __shared__ float red[4];
    if ((t & 63) == 0) red[t >> 6] = local;
    __syncthreads();
    if (t == 0)
        n_out[s] = DECAY * (red[0] + red[1] + red[2] + red[3]) + OMD * (float)B_;
}

__global__ void __launch_bounds__(256)
gather_hist_kernel(const int* __restrict__ idx,
                   const float* __restrict__ emb,
                   float* __restrict__ z_q,
                   int* __restrict__ counts) {
    const int s     = blockIdx.x & (S_ - 1);
    const int chunk = blockIdx.x >> 5;
    const int g     = threadIdx.x >> 5;
    const int lane  = threadIdx.x & 31;
    const int b     = chunk * 8 + g;
    const int row   = b * S_ + s;
    const int k     = idx[row];
    if (lane == 0) atomicAdd(&counts[s * K_ + k], 1);
    const f4 val =
        reinterpret_cast<const f4*>(emb)[((size_t)s * K_ + k) * 32 + lane];
    reinterpret_cast<f4*>(z_q)[(size_t)row * 32 + lane] = val;
}

__global__ void __launch_bounds__(256)
ema_kernel(const float* __restrict__ ema_w,
           const float* __restrict__ emb,
           const float* __restrict__ ecs_in,
           const int* __restrict__ counts,
           const float* __restrict__ n_arr,
           float* __restrict__ new_ecs_out,
           float* __restrict__ new_ema_w_out,
           float* __restrict__ new_emb_out) {
    const int i = blockIdx.x;
    const int s = i & (S_ - 1);
    const int c = i >> 5;
    const size_t base = ((size_t)s * K_ + c * 32) * 32;
    const float n = n_arr[s];
    const float denom_inv = 1.0f / (n + (float)K_ * EPS);
#pragma unroll
    for (int it = 0; it < 4; ++it) {
        const size_t e = base + it * 256 + threadIdx.x;
        const int sk = (int)(e >> 5);
        const float ccount = (float)counts[sk];
        const float ne = DECAY * ecs_in[sk] + OMD * ccount;
        const float cs = (ne + EPS) * denom_inv * n;
        if ((e & 31) == 0) new_ecs_out[sk] = ne;
        const f4 w  = reinterpret_cast<const f4*>(ema_w)[e];
        const f4 em = reinterpret_cast<const f4*>(emb)[e];
        f4 nw;
        nw.x = DECAY * w.x + OMD * ccount * em.x;
        nw.y = DECAY * w.y + OMD * ccount * em.y;
        nw.z = DECAY * w.z + OMD * ccount * em.z;
        nw.w = DECAY * w.w + OMD * ccount * em.w;
        reinterpret_cast<f4*>(new_ema_w_out)[e] = nw;
        const float inv = 1.0f / cs;
        f4 nb;
        nb.x = nw.x * inv;
        nb.y = nw.y * inv;
        nb.z = nw.z * inv;
        nb.w = nw.w * inv;
        reinterpret_cast<f4*>(new_emb_out)[e] = nb;
    }
}

extern "C" void kernel_launch(void* const* d_in, const int* in_sizes, int n_in,
                              void* d_out, int out_size, void* d_ws, size_t ws_size,
                              hipStream_t stream) {
    const int*   idx   = (const int*)d_in[0];
    const float* emb   = (const float*)d_in[1];
    const float* ecs   = (const float*)d_in[2];
    const float* ema_w = (const float*)d_in[3];

    float* out       = (float*)d_out;
    float* z_q       = out;                                  // [B,S,D]
    float* new_emb   = z_q + (size_t)B_ * S_ * D_;           // [S,K,D]
    float* new_ecs   = new_emb + (size_t)S_ * K_ * D_;       // [S,K]
    float* new_ema_w = new_ecs + (size_t)S_ * K_;            // [S,K,D]

    if (ws_size >= (size_t)B_ * S_ * sizeof(u16)) {
        // Fast path: 2 kernels, idx_T in ws.
        u16* idx_t = (u16*)d_ws;
        gather_t_kernel<<<2048, 256, 0, stream>>>(idx, emb, z_q, idx_t);
        ema_hist_kernel<<<2048, 256, 0, stream>>>(
            idx_t, emb, ecs, ema_w, new_ecs, new_ema_w, new_emb);
    } else {
        // Fallback: proven R6 3-kernel path (counts + n in ws, 128.2 KB).
        int*   counts = (int*)d_ws;
        float* n_arr  = (float*)d_ws + (size_t)S_ * K_;
        init_kernel<<<S_, 256, 0, stream>>>(ecs, counts, n_arr);
        gather_hist_kernel<<<(B_ * S_) / 8, 256, 0, stream>>>(idx, emb, z_q, counts);
        ema_kernel<<<1024, 256, 0, stream>>>(
            ema_w, emb, ecs, counts, n_arr, new_ecs, new_ema_w, new_emb);
    }
}